// Round 5
// baseline (65.346 us; speedup 1.0000x reference)
//
#include <hip/hip_runtime.h>
#include <hip/hip_bf16.h>

// HMM forward via paired-step segmented matrix products (R5).
//
//   S_{t+1} S_t = diag(e_{t+1}) * G2[x_t],   G2[m] = A * diag(e_m) * A
//
// R5 = R3 (verified: absmax 0.0) + ONE change: x is eliminated from the hot
// loop. Each lane loads its observation pair (x[2i], x[2i+1]) once (nseg=32
// -> npair <= 64 == wave size), packed into one VGPR; the loop reads indices
// via v_readlane. No memory ops / no vmcnt drains in the steady state (R3
// stalled on readfirstlane(x[..]) -> s_waitcnt vmcnt(0) every 4 pairs).
// Setup, comb, f2bf RNE, f32 ET, Q layout kept verbatim from R3.

#define NS    16
#define MOBS  64
#define SSH   5            // log2(nseg); nseg=32 -> L<=128 -> npair<=64
#define NSEG  32

typedef float f32x4 __attribute__((ext_vector_type(4)));
typedef short s16x4 __attribute__((ext_vector_type(4)));

static __device__ __forceinline__ int imin(int a, int b){ return a < b ? a : b; }

static __device__ __forceinline__ unsigned short f2bf(float f){
  return __bfloat16_as_ushort(__float2bfloat16(f));   // RNE
}
static __device__ __forceinline__ float b2f(unsigned short u){
  unsigned bits = ((unsigned)u) << 16;
  return __builtin_bit_cast(float, bits);
}

#if __has_builtin(__builtin_amdgcn_mfma_f32_16x16x16bf16_1k)
static __device__ __forceinline__ f32x4 mfma16(s16x4 a, s16x4 b, f32x4 c){
  return __builtin_amdgcn_mfma_f32_16x16x16bf16_1k(a, b, c, 0, 0, 0);
}
#else
static __device__ __forceinline__ f32x4 mfma16(s16x4 a, s16x4 b, f32x4 c){
  f32x4 d;
  asm volatile("v_mfma_f32_16x16x16_bf16 %0, %1, %2, %3"
               : "=&v"(d) : "v"(a), "v"(b), "v"(c));
  return d;
}
#endif

// ---------------- ws byte layout ----------------
//     0 : ET  f32 [64][16], ET[m][i] = P(obs m | state i)   (4096 B)
//  4096 : pi  f32 [16]                                      (64 B)
//  8192 : G2  ushort [65][64][4] MFMA A-frags; slot 64 = A  (33280 B)
// 49152 : Q   ushort [B][NSEG][256]  (row-major [row][col])
//  then : CE  int    [B][NSEG][16]
// -------------------------------------------------

// One kernel: all softmax normalizations + G2 table build (verbatim R3).
__global__ void hmm_setup(const float* __restrict__ tl, const float* __restrict__ el,
                          const float* __restrict__ pl, float* __restrict__ ws,
                          unsigned short* __restrict__ g2)
{
  int m = blockIdx.x, t = threadIdx.x;   // 65 blocks x 256 threads
  __shared__ float Al[256];
  __shared__ float ev[16];
  if (t < 16){
    // A column t (softmax over rows, axis=0)
    float mx = -3.0e38f;
    for (int i = 0; i < 16; ++i) mx = fmaxf(mx, tl[i*NS + t]);
    float sm = 0.f;
    for (int i = 0; i < 16; ++i) sm += expf(tl[i*NS + t] - mx);
    float inv = 1.f / sm;
    for (int i = 0; i < 16; ++i) Al[i*16 + t] = expf(tl[i*NS + t] - mx) * inv;
  } else if (t < 32){
    int i = t - 16;
    if (m < 64){
      // e_m[i] = softmax_m(E row i) at column m ; also persist ET row m
      float mx = -3.0e38f;
      for (int mm = 0; mm < MOBS; ++mm) mx = fmaxf(mx, el[i*MOBS + mm]);
      float sm = 0.f;
      for (int mm = 0; mm < MOBS; ++mm) sm += expf(el[i*MOBS + mm] - mx);
      float v = expf(el[i*MOBS + m] - mx) / sm;
      ev[i] = v;
      ws[m*16 + i] = v;
    } else ev[i] = 1.f;
  } else if (t < 48 && m == 64){
    int i = t - 32;
    float mx = -3.0e38f;
    for (int k = 0; k < 16; ++k) mx = fmaxf(mx, pl[k]);
    float sm = 0.f;
    for (int k = 0; k < 16; ++k) sm += expf(pl[k] - mx);
    ws[1024 + i] = expf(pl[i] - mx) / sm;
  }
  __syncthreads();
  int l = t >> 2, e = t & 3;
  int i = l & 15, col = ((l >> 4) << 2) + e;    // A-frag: lane l = row l&15, cols 4*(l>>4)+e
  float acc;
  if (m == 64){
    acc = Al[i*16 + col];
  } else {
    acc = 0.f;
    #pragma unroll
    for (int k = 0; k < 16; ++k) acc += Al[i*16 + k] * ev[k] * Al[k*16 + col];
  }
  g2[(m*64 + l)*4 + e] = f2bf(acc);
}

// 4 pair-steps; prefetches quad+1's LDS fragments via readlane(xp, p0+4+p).
// MASK: pairs with p0+p >= npair computed (valid-but-garbage indices) but not
// committed. Math/renorm verbatim R3.
template<bool MASK>
static __device__ __forceinline__ void run_quad(
    int p0, int npair,
    const unsigned short* g2l, const float* etl, int lane4, int g4, int xp,
    s16x4& P, int& ce,
    s16x4 (&gf)[4], f32x4 (&ev)[4], s16x4 (&gfn)[4], f32x4 (&evn)[4])
{
  const f32x4 Z = {0.f, 0.f, 0.f, 0.f};
  #pragma unroll
  for (int p = 0; p < 4; ++p){
    int v = __builtin_amdgcn_readlane(xp, (p0 + 4 + p) & 63);
    gfn[p] = *(const s16x4*)&g2l[(v & 63)*256 + lane4];
    evn[p] = *(const f32x4*)&etl[((v >> 8) & 63)*16 + g4];

    f32x4 C = mfma16(gf[p], P, Z);               // C = G2[x_t] * P
    C.x *= ev[p].x; C.y *= ev[p].y;              // rows scaled by e_{t+1}
    C.z *= ev[p].z; C.w *= ev[p].w;

    bool commit = (!MASK) || (p0 + p < npair);
    if (p == 3){
      float mm = fmaxf(fmaxf(C.x, C.y), fmaxf(C.z, C.w));
      mm = fmaxf(mm, __shfl_xor(mm, 16));
      mm = fmaxf(mm, __shfl_xor(mm, 32));
      int kk; (void)frexpf(mm, &kk);
      if (commit){
        C.x = ldexpf(C.x, -kk); C.y = ldexpf(C.y, -kk);
        C.z = ldexpf(C.z, -kk); C.w = ldexpf(C.w, -kk);
        ce += kk;
      }
    }
    if (commit){
      s16x4 Pn;
      Pn.x = (short)f2bf(C.x); Pn.y = (short)f2bf(C.y);
      Pn.z = (short)f2bf(C.z); Pn.w = (short)f2bf(C.w);
      P = Pn;                                    // C layout == B layout (R0-verified)
    }
  }
}

__global__ __launch_bounds__(512, 1) void hmm_seg(
    const int* __restrict__ x, const int* __restrict__ Tl,
    const float* __restrict__ ws, const unsigned short* __restrict__ g2,
    unsigned short* __restrict__ Q, int* __restrict__ CE,
    int TMAX, int XN)
{
  __shared__ unsigned short g2l[64*256];   // 32768 B
  __shared__ float etl[1024];              //  4096 B -> 36864 total
  {
    const uint4* src = (const uint4*)g2;   // first 64 slots: 2048 uint4
    uint4* dst = (uint4*)g2l;
    for (int i = threadIdx.x; i < 2048; i += 512) dst[i] = src[i];
    const float4* es = (const float4*)ws;
    float4* ed = (float4*)etl;
    if (threadIdx.x < 256) ed[threadIdx.x] = es[threadIdx.x];
  }
  __syncthreads();

  int tid  = threadIdx.x;
  int lane = tid & 63;
  int wid  = __builtin_amdgcn_readfirstlane(tid >> 6);
  int g = lane >> 4, j = lane & 15;
  int lane4 = lane * 4, g4 = g * 4;

  int gseg = blockIdx.x * 8 + wid;
  int b = gseg >> SSH, s = gseg & (NSEG - 1);

  int steps = __builtin_amdgcn_readfirstlane(Tl[b]) - 1;
  int L  = (steps + NSEG - 1) >> SSH;       // even split; L <= 128 -> npair <= 64
  int lo = s * L;
  int n  = imin(steps - lo, L);

  unsigned short* Qout = Q + (size_t)gseg * 256;
  int* ceout = CE + gseg * NS;

  if (n <= 0){                              // empty segment -> identity
    if (g == 0) ceout[j] = 0;
    #pragma unroll
    for (int e = 0; e < 4; ++e){
      int k = 4*g + e;
      Qout[k*16 + j] = (k == j) ? (unsigned short)0x3F80 : (unsigned short)0;
    }
    return;
  }

  int npair = n >> 1, odd = n & 1;
  int xbase = b*TMAX + 1 + lo;

  // lane i holds packed observation pair (x[2i], x[2i+1]) for the whole segment
  int i0 = xbase + 2*lane;
  int xa = x[imin(i0,     XN - 1)] & 63;
  int xb = x[imin(i0 + 1, XN - 1)] & 63;
  int xp = xa | (xb << 8);

  s16x4 P;                                  // identity in B-frag layout
  P.x = (4*g+0 == j) ? (short)0x3F80 : (short)0;
  P.y = (4*g+1 == j) ? (short)0x3F80 : (short)0;
  P.z = (4*g+2 == j) ? (short)0x3F80 : (short)0;
  P.w = (4*g+3 == j) ? (short)0x3F80 : (short)0;

  s16x4 gfA[4], gfB[4];
  f32x4 evA[4], evB[4];
  #pragma unroll
  for (int p = 0; p < 4; ++p){
    int v = __builtin_amdgcn_readlane(xp, p);
    gfA[p] = *(const s16x4*)&g2l[(v & 63)*256 + lane4];
    evA[p] = *(const f32x4*)&etl[((v >> 8) & 63)*16 + g4];
  }

  int ce = 0, p0 = 0;
  while (p0 + 8 <= npair){
    run_quad<false>(p0,   npair, g2l, etl, lane4, g4, xp, P, ce, gfA, evA, gfB, evB);
    run_quad<false>(p0+4, npair, g2l, etl, lane4, g4, xp, P, ce, gfB, evB, gfA, evA);
    p0 += 8;
  }
  if (p0 < npair){
    run_quad<true>(p0, npair, g2l, etl, lane4, g4, xp, P, ce, gfA, evA, gfB, evB);
    if (p0 + 4 < npair)
      run_quad<true>(p0+4, npair, g2l, etl, lane4, g4, xp, P, ce, gfB, evB, gfA, evA);
  }

  if (odd){                                 // trailing single step: diag(e)*A
    int v = __builtin_amdgcn_readlane(xp, (n - 1) >> 1);
    int xm = v & 63;                        // n-1 even -> first obs of that pair
    s16x4 af = *(const s16x4*)&g2[16384 + lane4];    // slot 64 = A frag
    f32x4 evo = *(const f32x4*)&etl[xm*16 + g4];
    const f32x4 Z = {0.f,0.f,0.f,0.f};
    f32x4 C = mfma16(af, P, Z);
    C.x *= evo.x; C.y *= evo.y; C.z *= evo.z; C.w *= evo.w;
    P.x = (short)f2bf(C.x); P.y = (short)f2bf(C.y);
    P.z = (short)f2bf(C.z); P.w = (short)f2bf(C.w);
  }

  if (g == 0) ceout[j] = ce;
  unsigned short pb[4] = {(unsigned short)P.x, (unsigned short)P.y,
                          (unsigned short)P.z, (unsigned short)P.w};
  #pragma unroll
  for (int e = 0; e < 4; ++e) Qout[(4*g + e)*16 + j] = pb[e];
}

// Combine (verbatim R3): 4 batches/block, one wave per batch, shuffle-only
// matvec; Q row-major [row][col].
__global__ __launch_bounds__(256) void hmm_comb(
    const int* __restrict__ x, const float* __restrict__ ws,
    const unsigned short* __restrict__ Q, const int* __restrict__ CE,
    float* __restrict__ out, int TMAX, int nseg)
{
  int lane = threadIdx.x & 63;
  int w    = threadIdx.x >> 6;
  int b    = blockIdx.x * 4 + w;
  int k = lane & 15, r = lane >> 4;

  int x0 = x[b*TMAX];
  float u = ws[1024 + k] * ws[x0*16 + k];   // alpha0 = pi * E[:,x0]
  int ce_tot = 0;

  for (int s = 0; s < nseg; ++s){
    const unsigned short* q = Q + (size_t)(b*nseg + s) * 256;
    int cek = CE[(b*nseg + s)*NS + k];
    int cmx = cek;
    cmx = max(cmx, __shfl_xor(cmx, 1));
    cmx = max(cmx, __shfl_xor(cmx, 2));
    cmx = max(cmx, __shfl_xor(cmx, 4));
    cmx = max(cmx, __shfl_xor(cmx, 8));
    float us = ldexpf(u, cek - cmx);        // undo per-column scaling
    ce_tot += cmx;

    float u0 = __shfl(us, 4*r + 0);
    float u1 = __shfl(us, 4*r + 1);
    float u2 = __shfl(us, 4*r + 2);
    float u3 = __shfl(us, 4*r + 3);
    s16x4 qq = *(const s16x4*)&q[k*16 + 4*r];
    float acc = b2f((unsigned short)qq.x)*u0 + b2f((unsigned short)qq.y)*u1
              + b2f((unsigned short)qq.z)*u2 + b2f((unsigned short)qq.w)*u3;
    acc += __shfl_xor(acc, 16);
    acc += __shfl_xor(acc, 32);

    float mu = acc;
    mu = fmaxf(mu, __shfl_xor(mu, 1));
    mu = fmaxf(mu, __shfl_xor(mu, 2));
    mu = fmaxf(mu, __shfl_xor(mu, 4));
    mu = fmaxf(mu, __shfl_xor(mu, 8));
    int kk; (void)frexpf(mu, &kk);
    u = ldexpf(acc, -kk);
    ce_tot += kk;
  }

  float sm = u;
  sm += __shfl_xor(sm, 1);
  sm += __shfl_xor(sm, 2);
  sm += __shfl_xor(sm, 4);
  sm += __shfl_xor(sm, 8);
  if (lane == 0) out[b] = ldexpf(sm, ce_tot);
}

extern "C" void kernel_launch(void* const* d_in, const int* in_sizes, int n_in,
                              void* d_out, int out_size, void* d_ws, size_t ws_size,
                              hipStream_t stream)
{
  (void)n_in; (void)out_size; (void)ws_size;
  const int*   x  = (const int*)  d_in[0];
  const int*   T  = (const int*)  d_in[1];
  const float* tl = (const float*)d_in[2];
  const float* el = (const float*)d_in[3];
  const float* pl = (const float*)d_in[4];
  int B    = in_sizes[1];
  int TMAX = in_sizes[0] / B;
  int XN   = B * TMAX;

  float* ws = (float*)d_ws;
  unsigned short* g2 = (unsigned short*)((char*)d_ws + 8192);
  unsigned short* Q  = (unsigned short*)((char*)d_ws + 49152);
  int* CE = (int*)((char*)d_ws + 49152 + (size_t)B * NSEG * 512);
  float* out = (float*)d_out;

  hipLaunchKernelGGL(hmm_setup, dim3(65),          dim3(256), 0, stream, tl, el, pl, ws, g2);
  hipLaunchKernelGGL(hmm_seg,   dim3(B*NSEG/8),    dim3(512), 0, stream, x, T, ws, g2, Q, CE, TMAX, XN);
  hipLaunchKernelGGL(hmm_comb,  dim3(B/4),         dim3(256), 0, stream, x, ws, Q, CE, out, TMAX, NSEG);
}

// Round 6
// 60.950 us; speedup vs baseline: 1.0721x; 1.0721x over previous
//
#include <hip/hip_runtime.h>
#include <hip/hip_bf16.h>

// HMM forward via paired-step segmented matrix products (R6).
//
//   S_{t+1} S_t = diag(e_{t+1}) * G2[x_t],   G2[m] = A * diag(e_m) * A
//
// R6 = R5 (verified: absmax 0.0) + exactly two changes:
//  1. P->bf16 via v_cvt_pk_bf16_f32 (2 instr) instead of software RNE (~20).
//     Also serves as the bisect of R4's NaN (R4 bundled this with 4 other
//     changes; if R6 NaNs, cvt_pk is pinned as the culprit).
//  2. Blocks whose 8 segments are all empty (lowest seg index >= steps)
//     write identities and exit BEFORE the 36.8KB LDS staging.
// Everything else verbatim R5.

#define NS    16
#define MOBS  64
#define SSH   5            // log2(nseg); nseg=32 -> L<=128 -> npair<=64
#define NSEG  32

typedef float f32x4 __attribute__((ext_vector_type(4)));
typedef short s16x4 __attribute__((ext_vector_type(4)));

static __device__ __forceinline__ int imin(int a, int b){ return a < b ? a : b; }

static __device__ __forceinline__ unsigned short f2bf(float f){
  return __bfloat16_as_ushort(__float2bfloat16(f));   // RNE (setup only)
}
static __device__ __forceinline__ float b2f(unsigned short u){
  unsigned bits = ((unsigned)u) << 16;
  return __builtin_bit_cast(float, bits);
}

// packed f32x2 -> bf16x2 (hardware RNE; no builtin on gfx950 -> inline asm)
static __device__ __forceinline__ s16x4 pack_bf16x4(f32x4 C){
  unsigned r0, r1;
  asm("v_cvt_pk_bf16_f32 %0, %1, %2" : "=v"(r0) : "v"(C.x), "v"(C.y));
  asm("v_cvt_pk_bf16_f32 %0, %1, %2" : "=v"(r1) : "v"(C.z), "v"(C.w));
  uint2 pu; pu.x = r0; pu.y = r1;
  return __builtin_bit_cast(s16x4, pu);
}

#if __has_builtin(__builtin_amdgcn_mfma_f32_16x16x16bf16_1k)
static __device__ __forceinline__ f32x4 mfma16(s16x4 a, s16x4 b, f32x4 c){
  return __builtin_amdgcn_mfma_f32_16x16x16bf16_1k(a, b, c, 0, 0, 0);
}
#else
static __device__ __forceinline__ f32x4 mfma16(s16x4 a, s16x4 b, f32x4 c){
  f32x4 d;
  asm volatile("v_mfma_f32_16x16x16_bf16 %0, %1, %2, %3"
               : "=&v"(d) : "v"(a), "v"(b), "v"(c));
  return d;
}
#endif

// ---------------- ws byte layout ----------------
//     0 : ET  f32 [64][16], ET[m][i] = P(obs m | state i)   (4096 B)
//  4096 : pi  f32 [16]                                      (64 B)
//  8192 : G2  ushort [65][64][4] MFMA A-frags; slot 64 = A  (33280 B)
// 49152 : Q   ushort [B][NSEG][256]  (row-major [row][col])
//  then : CE  int    [B][NSEG][16]
// -------------------------------------------------

// One kernel: all softmax normalizations + G2 table build (verbatim R3/R5).
__global__ void hmm_setup(const float* __restrict__ tl, const float* __restrict__ el,
                          const float* __restrict__ pl, float* __restrict__ ws,
                          unsigned short* __restrict__ g2)
{
  int m = blockIdx.x, t = threadIdx.x;   // 65 blocks x 256 threads
  __shared__ float Al[256];
  __shared__ float ev[16];
  if (t < 16){
    // A column t (softmax over rows, axis=0)
    float mx = -3.0e38f;
    for (int i = 0; i < 16; ++i) mx = fmaxf(mx, tl[i*NS + t]);
    float sm = 0.f;
    for (int i = 0; i < 16; ++i) sm += expf(tl[i*NS + t] - mx);
    float inv = 1.f / sm;
    for (int i = 0; i < 16; ++i) Al[i*16 + t] = expf(tl[i*NS + t] - mx) * inv;
  } else if (t < 32){
    int i = t - 16;
    if (m < 64){
      // e_m[i] = softmax_m(E row i) at column m ; also persist ET row m
      float mx = -3.0e38f;
      for (int mm = 0; mm < MOBS; ++mm) mx = fmaxf(mx, el[i*MOBS + mm]);
      float sm = 0.f;
      for (int mm = 0; mm < MOBS; ++mm) sm += expf(el[i*MOBS + mm] - mx);
      float v = expf(el[i*MOBS + m] - mx) / sm;
      ev[i] = v;
      ws[m*16 + i] = v;
    } else ev[i] = 1.f;
  } else if (t < 48 && m == 64){
    int i = t - 32;
    float mx = -3.0e38f;
    for (int k = 0; k < 16; ++k) mx = fmaxf(mx, pl[k]);
    float sm = 0.f;
    for (int k = 0; k < 16; ++k) sm += expf(pl[k] - mx);
    ws[1024 + i] = expf(pl[i] - mx) / sm;
  }
  __syncthreads();
  int l = t >> 2, e = t & 3;
  int i = l & 15, col = ((l >> 4) << 2) + e;    // A-frag: lane l = row l&15, cols 4*(l>>4)+e
  float acc;
  if (m == 64){
    acc = Al[i*16 + col];
  } else {
    acc = 0.f;
    #pragma unroll
    for (int k = 0; k < 16; ++k) acc += Al[i*16 + k] * ev[k] * Al[k*16 + col];
  }
  g2[(m*64 + l)*4 + e] = f2bf(acc);
}

// 4 pair-steps; prefetches quad+1's LDS fragments via readlane(xp, p0+4+p).
// MASK: pairs with p0+p >= npair computed (valid-but-garbage indices) but not
// committed.
template<bool MASK>
static __device__ __forceinline__ void run_quad(
    int p0, int npair,
    const unsigned short* g2l, const float* etl, int lane4, int g4, int xp,
    s16x4& P, int& ce,
    s16x4 (&gf)[4], f32x4 (&ev)[4], s16x4 (&gfn)[4], f32x4 (&evn)[4])
{
  const f32x4 Z = {0.f, 0.f, 0.f, 0.f};
  #pragma unroll
  for (int p = 0; p < 4; ++p){
    int v = __builtin_amdgcn_readlane(xp, (p0 + 4 + p) & 63);
    gfn[p] = *(const s16x4*)&g2l[(v & 63)*256 + lane4];
    evn[p] = *(const f32x4*)&etl[((v >> 8) & 63)*16 + g4];

    f32x4 C = mfma16(gf[p], P, Z);               // C = G2[x_t] * P
    C.x *= ev[p].x; C.y *= ev[p].y;              // rows scaled by e_{t+1}
    C.z *= ev[p].z; C.w *= ev[p].w;

    bool commit = (!MASK) || (p0 + p < npair);
    if (p == 3){
      float mm = fmaxf(fmaxf(C.x, C.y), fmaxf(C.z, C.w));
      mm = fmaxf(mm, __shfl_xor(mm, 16));
      mm = fmaxf(mm, __shfl_xor(mm, 32));
      int kk; (void)frexpf(mm, &kk);
      if (commit){
        C.x = ldexpf(C.x, -kk); C.y = ldexpf(C.y, -kk);
        C.z = ldexpf(C.z, -kk); C.w = ldexpf(C.w, -kk);
        ce += kk;
      }
    }
    if (commit){
      P = pack_bf16x4(C);                        // C layout == B layout (R0-verified)
    }
  }
}

__global__ __launch_bounds__(512, 1) void hmm_seg(
    const int* __restrict__ x, const int* __restrict__ Tl,
    const float* __restrict__ ws, const unsigned short* __restrict__ g2,
    unsigned short* __restrict__ Q, int* __restrict__ CE,
    int TMAX, int XN)
{
  int tid  = threadIdx.x;
  int lane = tid & 63;
  int wid  = __builtin_amdgcn_readfirstlane(tid >> 6);
  int g = lane >> 4, j = lane & 15;
  int lane4 = lane * 4, g4 = g * 4;

  int gseg = blockIdx.x * 8 + wid;
  int b = gseg >> SSH, s = gseg & (NSEG - 1);

  int steps = __builtin_amdgcn_readfirstlane(Tl[b]) - 1;
  int L  = (steps + NSEG - 1) >> SSH;       // even split; L <= 128 -> npair <= 64
  int lo = s * L;
  int n  = imin(steps - lo, L);

  unsigned short* Qout = Q + (size_t)gseg * 256;
  int* ceout = CE + gseg * NS;

  // Block-level fast path: all 8 segments of this block empty -> identities,
  // exit BEFORE LDS staging. Condition is block-uniform (same b for all 8
  // waves; lowest segment index of the block = (blockIdx&3)*8).
  int s_lo = (blockIdx.x & 3) * 8;
  if (s_lo * L >= steps){
    if (g == 0) ceout[j] = 0;
    #pragma unroll
    for (int e = 0; e < 4; ++e){
      int k = 4*g + e;
      Qout[k*16 + j] = (k == j) ? (unsigned short)0x3F80 : (unsigned short)0;
    }
    return;
  }

  __shared__ unsigned short g2l[64*256];   // 32768 B
  __shared__ float etl[1024];              //  4096 B -> 36864 total
  {
    const uint4* src = (const uint4*)g2;   // first 64 slots: 2048 uint4
    uint4* dst = (uint4*)g2l;
    for (int i = tid; i < 2048; i += 512) dst[i] = src[i];
    const float4* es = (const float4*)ws;
    float4* ed = (float4*)etl;
    if (tid < 256) ed[tid] = es[tid];
  }
  __syncthreads();

  if (n <= 0){                              // this wave's segment empty -> identity
    if (g == 0) ceout[j] = 0;
    #pragma unroll
    for (int e = 0; e < 4; ++e){
      int k = 4*g + e;
      Qout[k*16 + j] = (k == j) ? (unsigned short)0x3F80 : (unsigned short)0;
    }
    return;
  }

  int npair = n >> 1, odd = n & 1;
  int xbase = b*TMAX + 1 + lo;

  // lane i holds packed observation pair (x[2i], x[2i+1]) for the whole segment
  int i0 = xbase + 2*lane;
  int xa = x[imin(i0,     XN - 1)] & 63;
  int xb = x[imin(i0 + 1, XN - 1)] & 63;
  int xp = xa | (xb << 8);

  s16x4 P;                                  // identity in B-frag layout
  P.x = (4*g+0 == j) ? (short)0x3F80 : (short)0;
  P.y = (4*g+1 == j) ? (short)0x3F80 : (short)0;
  P.z = (4*g+2 == j) ? (short)0x3F80 : (short)0;
  P.w = (4*g+3 == j) ? (short)0x3F80 : (short)0;

  s16x4 gfA[4], gfB[4];
  f32x4 evA[4], evB[4];
  #pragma unroll
  for (int p = 0; p < 4; ++p){
    int v = __builtin_amdgcn_readlane(xp, p);
    gfA[p] = *(const s16x4*)&g2l[(v & 63)*256 + lane4];
    evA[p] = *(const f32x4*)&etl[((v >> 8) & 63)*16 + g4];
  }

  int ce = 0, p0 = 0;
  while (p0 + 8 <= npair){
    run_quad<false>(p0,   npair, g2l, etl, lane4, g4, xp, P, ce, gfA, evA, gfB, evB);
    run_quad<false>(p0+4, npair, g2l, etl, lane4, g4, xp, P, ce, gfB, evB, gfA, evA);
    p0 += 8;
  }
  if (p0 < npair){
    run_quad<true>(p0, npair, g2l, etl, lane4, g4, xp, P, ce, gfA, evA, gfB, evB);
    if (p0 + 4 < npair)
      run_quad<true>(p0+4, npair, g2l, etl, lane4, g4, xp, P, ce, gfB, evB, gfA, evA);
  }

  if (odd){                                 // trailing single step: diag(e)*A
    int v = __builtin_amdgcn_readlane(xp, (n - 1) >> 1);
    int xm = v & 63;                        // n-1 even -> first obs of that pair
    s16x4 af = *(const s16x4*)&g2[16384 + lane4];    // slot 64 = A frag
    f32x4 evo = *(const f32x4*)&etl[xm*16 + g4];
    const f32x4 Z = {0.f,0.f,0.f,0.f};
    f32x4 C = mfma16(af, P, Z);
    C.x *= evo.x; C.y *= evo.y; C.z *= evo.z; C.w *= evo.w;
    P = pack_bf16x4(C);
  }

  if (g == 0) ceout[j] = ce;
  unsigned short pb[4] = {(unsigned short)P.x, (unsigned short)P.y,
                          (unsigned short)P.z, (unsigned short)P.w};
  #pragma unroll
  for (int e = 0; e < 4; ++e) Qout[(4*g + e)*16 + j] = pb[e];
}

// Combine (verbatim R3/R5): 4 batches/block, one wave per batch, shuffle-only
// matvec; Q row-major [row][col].
__global__ __launch_bounds__(256) void hmm_comb(
    const int* __restrict__ x, const float* __restrict__ ws,
    const unsigned short* __restrict__ Q, const int* __restrict__ CE,
    float* __restrict__ out, int TMAX, int nseg)
{
  int lane = threadIdx.x & 63;
  int w    = threadIdx.x >> 6;
  int b    = blockIdx.x * 4 + w;
  int k = lane & 15, r = lane >> 4;

  int x0 = x[b*TMAX];
  float u = ws[1024 + k] * ws[x0*16 + k];   // alpha0 = pi * E[:,x0]
  int ce_tot = 0;

  for (int s = 0; s < nseg; ++s){
    const unsigned short* q = Q + (size_t)(b*nseg + s) * 256;
    int cek = CE[(b*nseg + s)*NS + k];
    int cmx = cek;
    cmx = max(cmx, __shfl_xor(cmx, 1));
    cmx = max(cmx, __shfl_xor(cmx, 2));
    cmx = max(cmx, __shfl_xor(cmx, 4));
    cmx = max(cmx, __shfl_xor(cmx, 8));
    float us = ldexpf(u, cek - cmx);        // undo per-column scaling
    ce_tot += cmx;

    float u0 = __shfl(us, 4*r + 0);
    float u1 = __shfl(us, 4*r + 1);
    float u2 = __shfl(us, 4*r + 2);
    float u3 = __shfl(us, 4*r + 3);
    s16x4 qq = *(const s16x4*)&q[k*16 + 4*r];
    float acc = b2f((unsigned short)qq.x)*u0 + b2f((unsigned short)qq.y)*u1
              + b2f((unsigned short)qq.z)*u2 + b2f((unsigned short)qq.w)*u3;
    acc += __shfl_xor(acc, 16);
    acc += __shfl_xor(acc, 32);

    float mu = acc;
    mu = fmaxf(mu, __shfl_xor(mu, 1));
    mu = fmaxf(mu, __shfl_xor(mu, 2));
    mu = fmaxf(mu, __shfl_xor(mu, 4));
    mu = fmaxf(mu, __shfl_xor(mu, 8));
    int kk; (void)frexpf(mu, &kk);
    u = ldexpf(acc, -kk);
    ce_tot += kk;
  }

  float sm = u;
  sm += __shfl_xor(sm, 1);
  sm += __shfl_xor(sm, 2);
  sm += __shfl_xor(sm, 4);
  sm += __shfl_xor(sm, 8);
  if (lane == 0) out[b] = ldexpf(sm, ce_tot);
}

extern "C" void kernel_launch(void* const* d_in, const int* in_sizes, int n_in,
                              void* d_out, int out_size, void* d_ws, size_t ws_size,
                              hipStream_t stream)
{
  (void)n_in; (void)out_size; (void)ws_size;
  const int*   x  = (const int*)  d_in[0];
  const int*   T  = (const int*)  d_in[1];
  const float* tl = (const float*)d_in[2];
  const float* el = (const float*)d_in[3];
  const float* pl = (const float*)d_in[4];
  int B    = in_sizes[1];
  int TMAX = in_sizes[0] / B;
  int XN   = B * TMAX;

  float* ws = (float*)d_ws;
  unsigned short* g2 = (unsigned short*)((char*)d_ws + 8192);
  unsigned short* Q  = (unsigned short*)((char*)d_ws + 49152);
  int* CE = (int*)((char*)d_ws + 49152 + (size_t)B * NSEG * 512);
  float* out = (float*)d_out;

  hipLaunchKernelGGL(hmm_setup, dim3(65),          dim3(256), 0, stream, tl, el, pl, ws, g2);
  hipLaunchKernelGGL(hmm_seg,   dim3(B*NSEG/8),    dim3(512), 0, stream, x, T, ws, g2, Q, CE, TMAX, XN);
  hipLaunchKernelGGL(hmm_comb,  dim3(B/4),         dim3(256), 0, stream, x, ws, Q, CE, out, TMAX, NSEG);
}

// Round 7
// 50.674 us; speedup vs baseline: 1.2895x; 1.2028x over previous
//
#include <hip/hip_runtime.h>
#include <hip/hip_bf16.h>

// HMM forward via paired-step segmented matrix products (R7).
//
//   S_{t+1} S_t = diag(e_{t+1}) * G2[x_t],   G2[m] = A * diag(e_m) * A
//
// R7 = R6 (verified) + three targeted changes:
//  1. comb: removed per-iteration exponent-max (4 serial shfls) and u-renorm
//     (4 serial shfls). Reference exponent = readlane(CE[col0]); matrix columns
//     scaled by ldexp(q, ce[c]-c0) on load; u rescaled once/segment by lane-0
//     frexp exponent. Serial chain ~1700cy -> ~430cy per segment.
//  2. seg: ET stored bf16 in LDS -> ev read is b64 not b128 (LDS pipe -33%).
//  3. seg: renorm every 8 pairs instead of 4 (P in [2^-80,1]: bf16-safe).

#define NS    16
#define MOBS  64
#define SSH   5            // log2(nseg); nseg=32 -> L<=128 -> npair<=64
#define NSEG  32

typedef float f32x4 __attribute__((ext_vector_type(4)));
typedef short s16x4 __attribute__((ext_vector_type(4)));

static __device__ __forceinline__ int imin(int a, int b){ return a < b ? a : b; }

static __device__ __forceinline__ unsigned short f2bf(float f){
  return __bfloat16_as_ushort(__float2bfloat16(f));   // RNE (setup only)
}
static __device__ __forceinline__ float b2f(unsigned short u){
  unsigned bits = ((unsigned)u) << 16;
  return __builtin_bit_cast(float, bits);
}

// packed f32x2 -> bf16x2 (hardware RNE; no builtin on gfx950 -> inline asm)
static __device__ __forceinline__ s16x4 pack_bf16x4(f32x4 C){
  unsigned r0, r1;
  asm("v_cvt_pk_bf16_f32 %0, %1, %2" : "=v"(r0) : "v"(C.x), "v"(C.y));
  asm("v_cvt_pk_bf16_f32 %0, %1, %2" : "=v"(r1) : "v"(C.z), "v"(C.w));
  uint2 pu; pu.x = r0; pu.y = r1;
  return __builtin_bit_cast(s16x4, pu);
}

#if __has_builtin(__builtin_amdgcn_mfma_f32_16x16x16bf16_1k)
static __device__ __forceinline__ f32x4 mfma16(s16x4 a, s16x4 b, f32x4 c){
  return __builtin_amdgcn_mfma_f32_16x16x16bf16_1k(a, b, c, 0, 0, 0);
}
#else
static __device__ __forceinline__ f32x4 mfma16(s16x4 a, s16x4 b, f32x4 c){
  f32x4 d;
  asm volatile("v_mfma_f32_16x16x16_bf16 %0, %1, %2, %3"
               : "=&v"(d) : "v"(a), "v"(b), "v"(c));
  return d;
}
#endif

// ---------------- ws byte layout ----------------
//     0 : ET  f32 [64][16], ET[m][i] = P(obs m | state i)   (4096 B)
//  4096 : pi  f32 [16]                                      (64 B)
//  8192 : g2  ushort:
//            [0,16384)      G2 slots 0..63 (MFMA A-frag order)
//            [16384,16640)  slot 64 = plain A frag (odd tails)
//            [16640,17664)  ET bf16 [64][16]
// 49152 : Q   ushort [B][NSEG][256]  (row-major [row][col])
//  then : CE  int    [B][NSEG][16]
// -------------------------------------------------

// One kernel: all softmax normalizations + G2 table build (R6 + 1 line: bf16 ET).
__global__ void hmm_setup(const float* __restrict__ tl, const float* __restrict__ el,
                          const float* __restrict__ pl, float* __restrict__ ws,
                          unsigned short* __restrict__ g2)
{
  int m = blockIdx.x, t = threadIdx.x;   // 65 blocks x 256 threads
  __shared__ float Al[256];
  __shared__ float ev[16];
  if (t < 16){
    // A column t (softmax over rows, axis=0)
    float mx = -3.0e38f;
    for (int i = 0; i < 16; ++i) mx = fmaxf(mx, tl[i*NS + t]);
    float sm = 0.f;
    for (int i = 0; i < 16; ++i) sm += expf(tl[i*NS + t] - mx);
    float inv = 1.f / sm;
    for (int i = 0; i < 16; ++i) Al[i*16 + t] = expf(tl[i*NS + t] - mx) * inv;
  } else if (t < 32){
    int i = t - 16;
    if (m < 64){
      // e_m[i] = softmax_m(E row i) at column m ; also persist ET row m
      float mx = -3.0e38f;
      for (int mm = 0; mm < MOBS; ++mm) mx = fmaxf(mx, el[i*MOBS + mm]);
      float sm = 0.f;
      for (int mm = 0; mm < MOBS; ++mm) sm += expf(el[i*MOBS + mm] - mx);
      float v = expf(el[i*MOBS + m] - mx) / sm;
      ev[i] = v;
      ws[m*16 + i] = v;
      g2[16640 + m*16 + i] = f2bf(v);      // bf16 ET for seg LDS
    } else ev[i] = 1.f;
  } else if (t < 48 && m == 64){
    int i = t - 32;
    float mx = -3.0e38f;
    for (int k = 0; k < 16; ++k) mx = fmaxf(mx, pl[k]);
    float sm = 0.f;
    for (int k = 0; k < 16; ++k) sm += expf(pl[k] - mx);
    ws[1024 + i] = expf(pl[i] - mx) / sm;
  }
  __syncthreads();
  int l = t >> 2, e = t & 3;
  int i = l & 15, col = ((l >> 4) << 2) + e;    // A-frag: lane l = row l&15, cols 4*(l>>4)+e
  float acc;
  if (m == 64){
    acc = Al[i*16 + col];
  } else {
    acc = 0.f;
    #pragma unroll
    for (int k = 0; k < 16; ++k) acc += Al[i*16 + k] * ev[k] * Al[k*16 + col];
  }
  g2[(m*64 + l)*4 + e] = f2bf(acc);
}

// 4 pair-steps; prefetches quad+1's LDS fragments via readlane(xp, p0+4+p).
// MASK: pairs with p0+p >= npair computed (valid-but-garbage indices) but not
// committed. REN: renorm at p==3 (applied every OTHER quad -> every 8 pairs).
template<bool MASK, bool REN>
static __device__ __forceinline__ void run_quad(
    int p0, int npair,
    const unsigned short* g2l, const unsigned short* etl,
    int lane4, int g4, int xp, s16x4& P, int& ce,
    s16x4 (&gf)[4], s16x4 (&ev)[4], s16x4 (&gfn)[4], s16x4 (&evn)[4])
{
  const f32x4 Z = {0.f, 0.f, 0.f, 0.f};
  #pragma unroll
  for (int p = 0; p < 4; ++p){
    int v = __builtin_amdgcn_readlane(xp, (p0 + 4 + p) & 63);
    gfn[p] = *(const s16x4*)&g2l[(v & 63)*256 + lane4];
    evn[p] = *(const s16x4*)&etl[((v >> 8) & 63)*16 + g4];

    f32x4 C = mfma16(gf[p], P, Z);               // C = G2[x_t] * P
    C.x *= b2f((unsigned short)ev[p].x);         // rows scaled by e_{t+1}
    C.y *= b2f((unsigned short)ev[p].y);
    C.z *= b2f((unsigned short)ev[p].z);
    C.w *= b2f((unsigned short)ev[p].w);

    bool commit = (!MASK) || (p0 + p < npair);
    if (REN && p == 3){
      float mm = fmaxf(fmaxf(C.x, C.y), fmaxf(C.z, C.w));
      mm = fmaxf(mm, __shfl_xor(mm, 16));
      mm = fmaxf(mm, __shfl_xor(mm, 32));
      int kk; (void)frexpf(mm, &kk);
      if (commit){
        C.x = ldexpf(C.x, -kk); C.y = ldexpf(C.y, -kk);
        C.z = ldexpf(C.z, -kk); C.w = ldexpf(C.w, -kk);
        ce += kk;
      }
    }
    if (commit){
      P = pack_bf16x4(C);                        // C layout == B layout (R0-verified)
    }
  }
}

__global__ __launch_bounds__(512, 1) void hmm_seg(
    const int* __restrict__ x, const int* __restrict__ Tl,
    const unsigned short* __restrict__ g2,
    unsigned short* __restrict__ Q, int* __restrict__ CE,
    int TMAX, int XN)
{
  int tid  = threadIdx.x;
  int lane = tid & 63;
  int wid  = __builtin_amdgcn_readfirstlane(tid >> 6);
  int g = lane >> 4, j = lane & 15;
  int lane4 = lane * 4, g4 = g * 4;

  int gseg = blockIdx.x * 8 + wid;
  int b = gseg >> SSH, s = gseg & (NSEG - 1);

  int steps = __builtin_amdgcn_readfirstlane(Tl[b]) - 1;
  int L  = (steps + NSEG - 1) >> SSH;       // even split; L <= 128 -> npair <= 64
  int lo = s * L;
  int n  = imin(steps - lo, L);

  unsigned short* Qout = Q + (size_t)gseg * 256;
  int* ceout = CE + gseg * NS;

  // Block-level fast path: all 8 segments of this block empty -> identities,
  // exit BEFORE LDS staging (block-uniform condition).
  int s_lo = (blockIdx.x & 3) * 8;
  if (s_lo * L >= steps){
    if (g == 0) ceout[j] = 0;
    #pragma unroll
    for (int e = 0; e < 4; ++e){
      int k = 4*g + e;
      Qout[k*16 + j] = (k == j) ? (unsigned short)0x3F80 : (unsigned short)0;
    }
    return;
  }

  __shared__ unsigned short g2l[64*256];   // 32768 B
  __shared__ unsigned short etl[1024];     //  2048 B -> 34816 total
  {
    const uint4* s1 = (const uint4*)g2;                 // 2048 x uint4 (G2)
    const uint4* s2 = (const uint4*)(g2 + 16640);       //  128 x uint4 (ET bf16)
    uint4* d1 = (uint4*)g2l;
    uint4* d2 = (uint4*)etl;
    for (int i = tid; i < 2048; i += 512) d1[i] = s1[i];
    if (tid < 128) d2[tid] = s2[tid];
  }
  __syncthreads();

  if (n <= 0){                              // this wave's segment empty -> identity
    if (g == 0) ceout[j] = 0;
    #pragma unroll
    for (int e = 0; e < 4; ++e){
      int k = 4*g + e;
      Qout[k*16 + j] = (k == j) ? (unsigned short)0x3F80 : (unsigned short)0;
    }
    return;
  }

  int npair = n >> 1, odd = n & 1;
  int xbase = b*TMAX + 1 + lo;

  // lane i holds packed observation pair (x[2i], x[2i+1]) for the whole segment
  int i0 = xbase + 2*lane;
  int xa = x[imin(i0,     XN - 1)] & 63;
  int xb = x[imin(i0 + 1, XN - 1)] & 63;
  int xp = xa | (xb << 8);

  s16x4 P;                                  // identity in B-frag layout
  P.x = (4*g+0 == j) ? (short)0x3F80 : (short)0;
  P.y = (4*g+1 == j) ? (short)0x3F80 : (short)0;
  P.z = (4*g+2 == j) ? (short)0x3F80 : (short)0;
  P.w = (4*g+3 == j) ? (short)0x3F80 : (short)0;

  s16x4 gfA[4], gfB[4], evA[4], evB[4];
  #pragma unroll
  for (int p = 0; p < 4; ++p){
    int v = __builtin_amdgcn_readlane(xp, p);
    gfA[p] = *(const s16x4*)&g2l[(v & 63)*256 + lane4];
    evA[p] = *(const s16x4*)&etl[((v >> 8) & 63)*16 + g4];
  }

  int ce = 0, p0 = 0;
  while (p0 + 8 <= npair){
    run_quad<false,false>(p0,   npair, g2l, etl, lane4, g4, xp, P, ce, gfA, evA, gfB, evB);
    run_quad<false,true >(p0+4, npair, g2l, etl, lane4, g4, xp, P, ce, gfB, evB, gfA, evA);
    p0 += 8;
  }
  if (p0 < npair){
    run_quad<true,true>(p0, npair, g2l, etl, lane4, g4, xp, P, ce, gfA, evA, gfB, evB);
    if (p0 + 4 < npair)
      run_quad<true,true>(p0+4, npair, g2l, etl, lane4, g4, xp, P, ce, gfB, evB, gfA, evA);
  }

  if (odd){                                 // trailing single step: diag(e)*A
    int v = __builtin_amdgcn_readlane(xp, (n - 1) >> 1);
    int xm = v & 63;                        // n-1 even -> first obs of that pair
    s16x4 af  = *(const s16x4*)&g2[16384 + lane4];   // slot 64 = A frag
    s16x4 evo = *(const s16x4*)&etl[xm*16 + g4];
    const f32x4 Z = {0.f,0.f,0.f,0.f};
    f32x4 C = mfma16(af, P, Z);
    C.x *= b2f((unsigned short)evo.x); C.y *= b2f((unsigned short)evo.y);
    C.z *= b2f((unsigned short)evo.z); C.w *= b2f((unsigned short)evo.w);
    P = pack_bf16x4(C);
  }

  if (g == 0) ceout[j] = ce;
  unsigned short pb[4] = {(unsigned short)P.x, (unsigned short)P.y,
                          (unsigned short)P.z, (unsigned short)P.w};
  #pragma unroll
  for (int e = 0; e < 4; ++e) Qout[(4*g + e)*16 + j] = pb[e];
}

// Combine (R7): 4 batches/block, one wave per batch. Per segment: columns of
// Q scaled by ldexp(q, ce[c]-c0) with c0 = readlane(CE[0]); one scalar ce_tot;
// u rescaled once/segment by lane-0's frexp exponent. No shfl max-chains.
__global__ __launch_bounds__(256) void hmm_comb(
    const int* __restrict__ x, const float* __restrict__ ws,
    const unsigned short* __restrict__ Q, const int* __restrict__ CE,
    float* __restrict__ out, int TMAX)
{
  int lane = threadIdx.x & 63;
  int w    = threadIdx.x >> 6;
  int b    = blockIdx.x * 4 + w;
  int k = lane & 15, r = lane >> 4;

  int x0 = x[b*TMAX];
  float u = ws[1024 + k] * ws[x0*16 + k];   // alpha0 = pi * E[:,x0]
  int ce_tot = 0;

  const unsigned short* qb = Q  + (size_t)b * NSEG * 256;
  const int*            cb = CE + b * NSEG * 16;

  // prefetch segment 0
  s16x4 qq = *(const s16x4*)&qb[k*16 + 4*r];       // row k, cols 4r..4r+3
  int4  cv = *(const int4*)&cb[4*r];               // ce[4r..4r+3]

  for (int s = 0; s < NSEG; ++s){
    s16x4 qn; int4 cn;
    if (s + 1 < NSEG){                             // prefetch next segment
      qn = *(const s16x4*)&qb[(s+1)*256 + k*16 + 4*r];
      cn = *(const int4*)&cb[(s+1)*16 + 4*r];
    }
    int c0 = __builtin_amdgcn_readlane(cv.x, 0);   // ce[0] (lane 0: k=0,r=0)
    float m0 = ldexpf(b2f((unsigned short)qq.x), cv.x - c0);
    float m1 = ldexpf(b2f((unsigned short)qq.y), cv.y - c0);
    float m2 = ldexpf(b2f((unsigned short)qq.z), cv.z - c0);
    float m3 = ldexpf(b2f((unsigned short)qq.w), cv.w - c0);

    float u0 = __shfl(u, 4*r + 0);
    float u1 = __shfl(u, 4*r + 1);
    float u2 = __shfl(u, 4*r + 2);
    float u3 = __shfl(u, 4*r + 3);
    float acc = m0*u0 + m1*u1 + m2*u2 + m3*u3;
    acc += __shfl_xor(acc, 16);
    acc += __shfl_xor(acc, 32);                    // full u_new[k] on all r-copies

    int ek; (void)frexpf(acc, &ek);                // exponent of own component
    int k0 = __builtin_amdgcn_readlane(ek, 0);     // rescale by component 0
    u = ldexpf(acc, -k0);
    ce_tot += c0 + k0;

    qq = qn; cv = cn;
  }

  float sm = u;
  sm += __shfl_xor(sm, 1);
  sm += __shfl_xor(sm, 2);
  sm += __shfl_xor(sm, 4);
  sm += __shfl_xor(sm, 8);
  if (lane == 0) out[b] = ldexpf(sm, ce_tot);
}

extern "C" void kernel_launch(void* const* d_in, const int* in_sizes, int n_in,
                              void* d_out, int out_size, void* d_ws, size_t ws_size,
                              hipStream_t stream)
{
  (void)n_in; (void)out_size; (void)ws_size;
  const int*   x  = (const int*)  d_in[0];
  const int*   T  = (const int*)  d_in[1];
  const float* tl = (const float*)d_in[2];
  const float* el = (const float*)d_in[3];
  const float* pl = (const float*)d_in[4];
  int B    = in_sizes[1];
  int TMAX = in_sizes[0] / B;
  int XN   = B * TMAX;

  float* ws = (float*)d_ws;
  unsigned short* g2 = (unsigned short*)((char*)d_ws + 8192);
  unsigned short* Q  = (unsigned short*)((char*)d_ws + 49152);
  int* CE = (int*)((char*)d_ws + 49152 + (size_t)B * NSEG * 512);
  float* out = (float*)d_out;

  hipLaunchKernelGGL(hmm_setup, dim3(65),          dim3(256), 0, stream, tl, el, pl, ws, g2);
  hipLaunchKernelGGL(hmm_seg,   dim3(B*NSEG/8),    dim3(512), 0, stream, x, T, g2, Q, CE, TMAX, XN);
  hipLaunchKernelGGL(hmm_comb,  dim3(B/4),         dim3(256), 0, stream, x, ws, Q, CE, out, TMAX);
}